// Round 8
// baseline (48.152 us; speedup 1.0000x reference)
//
#include <hip/hip_runtime.h>
#include <math.h>

constexpr int kN = 65536;
constexpr int kB = 16384;
constexpr int kTileW = 2560;   // tiered packed triangle: 16*64+16*48+16*32+16*16 words
constexpr int kBuckets = 1024; // bucket = g >> 6

static __device__ __forceinline__ float bcastf(float v, int lane) {
    union { float f; int i; } u;
    u.f = v;
    u.i = __builtin_amdgcn_readlane(u.i, lane);
    return u.f;
}

// async global->LDS; LDS dest = wave-uniform base + lane*size (active lanes only)
static __device__ __forceinline__ void gload_lds16(const float* g, float* l) {
    __builtin_amdgcn_global_load_lds(
        (const __attribute__((address_space(1))) void*)g,
        (__attribute__((address_space(3))) void*)l, 16, 0, 0);
}
static __device__ __forceinline__ void gload_lds4(const float* g, float* l) {
    __builtin_amdgcn_global_load_lds(
        (const __attribute__((address_space(1))) void*)g,
        (__attribute__((address_space(3))) void*)l, 4, 0, 0);
}

// tier layout: row j (tier t=j>>4, width w=64-16t) starts at
// off(t) + w*(j-16t), off(t) = 1024t - 128t(t-1)
static __device__ __forceinline__ int row_start(int j) {
    const int t = j >> 4;
    return 1024 * t - 128 * t * (t - 1) + (64 - 16 * t) * (j - 16 * t);
}

static __device__ __forceinline__ bool is_hot(int g) {
    return (g >= 63) && (g <= kN - 63);
}

// ---------------- sort-by-g pipeline (tiny kernels) ----------------

__global__ __launch_bounds__(1024) void gp_zero_hist(int* __restrict__ hist) {
    hist[threadIdx.x] = 0;
}

__global__ __launch_bounds__(1024) void gp_hist_kernel(
    const int* __restrict__ gidx, int* __restrict__ hist)
{
    const int i = (int)blockIdx.x * 1024 + (int)threadIdx.x;   // 16 blocks
    atomicAdd(&hist[gidx[i] >> 6], 1);
}

__global__ __launch_bounds__(1024) void gp_scan_kernel(
    const int* __restrict__ hist, int* __restrict__ base)
{
    __shared__ int wsum[16];
    const int t = (int)threadIdx.x, lane = t & 63, w = t >> 6;
    const int v = hist[t];
    int x = v;
    #pragma unroll
    for (int d = 1; d < 64; d <<= 1) {
        const int n = __shfl_up(x, d, 64);
        if (lane >= d) x += n;
    }
    if (lane == 63) wsum[w] = x;
    __syncthreads();
    if (t == 0) {
        int acc = 0;
        #pragma unroll
        for (int k = 0; k < 16; ++k) { const int s = wsum[k]; wsum[k] = acc; acc += s; }
    }
    __syncthreads();
    base[t] = x - v + wsum[w];     // exclusive prefix
}

__global__ __launch_bounds__(1024) void gp_scatter_kernel(
    const int* __restrict__ gidx, int* __restrict__ base, int* __restrict__ sorted)
{
    const int i = (int)blockIdx.x * 1024 + (int)threadIdx.x;   // 16 blocks
    const int pos = atomicAdd(&base[gidx[i] >> 6], 1);
    sorted[pos] = i;
}

// ---------------- solve ----------------

__global__ __launch_bounds__(64) void gp_solve_kernel(
    const float* __restrict__ Uv,
    const float* __restrict__ Vv,
    const float* __restrict__ mean,
    const float* __restrict__ mean_post,
    const float* __restrict__ y,
    const int*   __restrict__ gidx,
    const int*   __restrict__ crow_u,
    const int*   __restrict__ crow_v,
    const float* __restrict__ noise,
    const int*   __restrict__ sorted,
    float*       __restrict__ partial)
{
    __shared__ __align__(16) float myl[kTileW];

    const int lane = (int)threadIdx.x;          // 0..63
    // chunked XCD swizzle: XCD k owns sorted slots [k*2048, (k+1)*2048)
    // -> per-XCD Vv working set ~2MB, fits the 4MB private L2.
    const int bid  = (int)blockIdx.x;
    const int slot = ((bid & 7) << 11) | (bid >> 3);
    const int b    = sorted[slot];
    const int g    = gidx[b];

    const int  anc = g - 63 + lane;             // this lane's row index
    const bool vl  = (anc >= 0);

    // U row: crow_u[g] = 2016 + 64*(g-63) for g>=63 (U rows never shorten)
    const int L  = (g + 1 < 64) ? (g + 1) : 64;
    const int ub = (g >= 63) ? (2016 + 64 * (g - 63)) : crow_u[g];

    float uval = 0.0f, md = 0.0f;
    if (vl) {
        uval = Uv[ub + lane - (64 - L)];        // row g of U, last L slots
        md   = mean[anc] - mean_post[anc];
    }
    const float yg  = y[g];
    const float mpg = mean_post[g];

    if (is_hot(g)) {
        const float* base = Vv + 64 * (g - 63);  // contiguous 16KB row block
        // tier0: rows 0..15 full width (1024 words @ 0)
        {
            const float* src = base + 4 * lane;
            #pragma unroll
            for (int k = 0; k < 4; ++k)
                gload_lds16(src + 256 * k, myl + 256 * k);
        }
        // tier1: rows 16..31, width 48 (768 words @ 1024)
        #pragma unroll
        for (int k = 0; k < 3; ++k) {
            const int w   = 256 * k + 4 * lane;
            const int jj  = ((w >> 4) * 171) >> 9;   // exact (w/16)/3 for w<768
            const int col = w - 48 * jj;
            gload_lds16(base + 64 * (16 + jj) + col, myl + 1024 + 256 * k);
        }
        // tier2: rows 32..47, width 32 (512 words @ 1792)
        #pragma unroll
        for (int k = 0; k < 2; ++k) {
            const int w = 256 * k + 4 * lane;
            gload_lds16(base + 64 * (32 + (w >> 5)) + (w & 31), myl + 1792 + 256 * k);
        }
        // tier3: rows 48..63, width 16 (256 words @ 2304)
        {
            const int w = 4 * lane;
            gload_lds16(base + 64 * (48 + (w >> 4)) + (w & 15), myl + 2304);
        }
    } else {
        // rare (~32/16384 waves): g<63 (identity rows) or band tail (crow_v irregular)
        int rowbase = 0;
        if (vl) rowbase = crow_v[anc];
        for (int j = 0; j < 64; ++j) {
            const int rbj = __builtin_amdgcn_readlane(rowbase, j);
            const int dst = row_start(j);
            if (lane < 64 - j) {                 // exactly the consumed words
                if (g - 63 + j >= 0)
                    gload_lds4(Vv + rbj + lane, myl + dst);
                else
                    myl[dst + lane] = 0.0f;      // identity row: zero off-diag
            }
        }
    }
    // per-wave drain of global_load_lds (vmcnt) and ds_write (lgkm); the
    // "memory" clobber orders the ds_reads below behind this wait.
    asm volatile("s_waitcnt vmcnt(0) lgkmcnt(0)" ::: "memory");

    const int rs = row_start(lane);
    const float d0   = myl[rs];
    const float diag = vl ? d0 : 1.0f;           // identity rows: unit diagonal
    const float invd = 1.0f / diag;

    // v[i] = V_sub[lane][i] / diag_lane for i>=lane; i<lane reads prior rows'
    // garbage, provably unused before this lane's residual is consumed at
    // step i=lane. Paired reads -> ds_read2_b32 merge.
    const float* vrow = myl + (rs - lane);
    float v[64];
    #pragma unroll
    for (int i = 0; i < 64; i += 2) {
        const float a0 = vrow[i];
        const float a1 = vrow[i + 1];
        v[i]     = a0 * invd;
        v[i + 1] = a1 * invd;
    }

    // ---- pre-scaled dual-RHS back-substitution (unit diagonal) ----
    float r_e = (lane == 63) ? invd : 0.0f;      // D^-1 e_{63}
    float r_u = uval * invd;                     // D^-1 U_sub
    float acc_e = 0.0f, acc_u = 0.0f;

    #pragma unroll
    for (int i = 63; i >= 0; --i) {
        const float s_e = bcastf(r_e, i);        // x_i for RHS e
        const float s_u = bcastf(r_u, i);        // x_i for RHS u
        r_e = fmaf(-v[i], s_e, r_e);             // on lane i: v[i]=1 -> r=0
        r_u = fmaf(-v[i], s_u, r_u);
        acc_e = fmaf(s_e, s_e, acc_e);
        acc_u = fmaf(s_u, s_u, acc_u);
    }

    // ---- dot(U_sub, md) via wave reduction ----
    float dot = uval * md;
    #pragma unroll
    for (int m = 1; m < 64; m <<= 1)
        dot += __shfl_xor(dot, m, 64);

    const float ulast  = bcastf(uval, 63);       // U_values[crow_u[g+1]-1]
    const float vfirst = bcastf(diag, 63);       // V_values[crow_v[g]]

    if (lane == 0) {
        const float resid = yg - mpg;
        const float inv2n = 0.5f / noise[0];
        partial[slot] = __logf(ulast) - __logf(vfirst)
                      - 0.5f * dot * dot
                      - 0.5f * acc_u
                      - (resid * resid + acc_e) * inv2n;
    }
}

__global__ __launch_bounds__(1024) void gp_reduce_kernel(
    const float* __restrict__ partial,
    const float* __restrict__ noise,
    float*       __restrict__ out)
{
    __shared__ float ws[16];
    const int t = (int)threadIdx.x;
    float a = 0.0f;
    #pragma unroll
    for (int k = 0; k < 4; ++k) {                // 4096 float4 = 16384 floats
        const float4 p = reinterpret_cast<const float4*>(partial)[t + 1024 * k];
        a += (p.x + p.y) + (p.z + p.w);
    }
    #pragma unroll
    for (int m = 1; m < 64; m <<= 1)
        a += __shfl_xor(a, m, 64);
    if ((t & 63) == 0) ws[t >> 6] = a;
    __syncthreads();
    if (t == 0) {
        float tot = 0.0f;
        #pragma unroll
        for (int k = 0; k < 16; ++k) tot += ws[k];
        tot += -0.5f * (float)kB * logf(2.0f * 3.14159265358979323846f * noise[0]);
        out[0] = tot;
    }
}

extern "C" void kernel_launch(void* const* d_in, const int* in_sizes, int n_in,
                              void* d_out, int out_size, void* d_ws, size_t ws_size,
                              hipStream_t stream)
{
    const float* Uv        = (const float*)d_in[0];
    const float* Vv        = (const float*)d_in[1];
    const float* mean      = (const float*)d_in[2];
    const float* mean_post = (const float*)d_in[3];
    const float* y         = (const float*)d_in[4];
    const float* noise     = (const float*)d_in[5];
    const int*   gidx      = (const int*)d_in[6];
    const int*   crow_u    = (const int*)d_in[7];
    const int*   crow_v    = (const int*)d_in[8];

    // ws layout (ints): sorted[16384] | hist[1024] | base[1024] | partial[16384]f
    int*   ws_i    = (int*)d_ws;
    int*   sorted  = ws_i;
    int*   hist    = ws_i + kB;
    int*   base    = ws_i + kB + kBuckets;
    float* partial = (float*)(ws_i + kB + 2 * kBuckets);   // 16B-aligned (73728B)

    gp_zero_hist   <<<dim3(1),       dim3(1024), 0, stream>>>(hist);
    gp_hist_kernel <<<dim3(kB/1024), dim3(1024), 0, stream>>>(gidx, hist);
    gp_scan_kernel <<<dim3(1),       dim3(1024), 0, stream>>>(hist, base);
    gp_scatter_kernel<<<dim3(kB/1024), dim3(1024), 0, stream>>>(gidx, base, sorted);

    gp_solve_kernel<<<dim3(kB), dim3(64), 0, stream>>>(
        Uv, Vv, mean, mean_post, y, gidx, crow_u, crow_v, noise, sorted, partial);
    gp_reduce_kernel<<<dim3(1), dim3(1024), 0, stream>>>(
        partial, noise, (float*)d_out);
}